// Round 5
// baseline (142.310 us; speedup 1.0000x reference)
//
#include <hip/hip_runtime.h>
#include <hip/hip_fp16.h>

#define BB 16
#define NN 1024
#define LALPHA 0.2f
#define MAXD 192

// ---------------- K1: fused CSR build (blocks 512..1535) + gemm1 (blocks 0..511) ----------
// gemm1: h1[m,f] = concat(X,state)[m,:] @ W1, fp16 out; s_src1/s_dst1 score epilogue.
__global__ __launch_bounds__(256) void csr_gemm1(
    const float* __restrict__ adj, const float* __restrict__ X,
    const float* __restrict__ state, const float* __restrict__ W1,
    const float* __restrict__ a1, int* __restrict__ deg, int* __restrict__ cols,
    __half* __restrict__ h1, float* __restrict__ ssrc1, float* __restrict__ sdst1) {
    __shared__ __align__(16) float xs[32][132];
    __shared__ int cnt;
    int t = threadIdx.x;

    if (blockIdx.x >= 512) {
        // ---- CSR branch: one block per node ----
        int i = blockIdx.x - 512;
        if (t == 0) cnt = 0;
        __syncthreads();
        for (int j = t; j < NN; j += 256) {
            if (adj[(size_t)i * NN + j] > 0.0f) {
                int p = atomicAdd(&cnt, 1);
                if (p < MAXD) cols[(size_t)i * MAXD + p] = j;
            }
        }
        __syncthreads();
        if (t == 0) deg[i] = cnt < MAXD ? cnt : MAXD;
        return;
    }

    // ---- gemm1 branch: 32 rows x 128 cols, K=128 ----
    int tf = t & 31, tr = t >> 5;     // col group (4 cols), row group (4 rows)
    int f0 = tf * 4, r0 = tr * 4;
    int base = blockIdx.x * 32;

    for (int idx = t; idx < 32 * 32; idx += 256) {
        int r = idx >> 5, c = (idx & 31) * 4;
        float4 v = (c < 64) ? *(const float4*)(X + (size_t)(base + r) * 64 + c)
                            : *(const float4*)(state + (size_t)(base + r) * 64 + (c - 64));
        xs[r][c] = v.x; xs[r][c + 1] = v.y; xs[r][c + 2] = v.z; xs[r][c + 3] = v.w;
    }
    __syncthreads();

    float acc[4][4] = {};
    for (int k = 0; k < 128; k += 4) {
        float4 xv[4], wv[4];
#pragma unroll
        for (int i = 0; i < 4; i++) xv[i] = *(const float4*)&xs[r0 + i][k];
#pragma unroll
        for (int i = 0; i < 4; i++) wv[i] = *(const float4*)(W1 + (size_t)(k + i) * 128 + f0);
#pragma unroll
        for (int i = 0; i < 4; i++) {
            float xr[4] = {xv[i].x, xv[i].y, xv[i].z, xv[i].w};
#pragma unroll
            for (int kk = 0; kk < 4; kk++) {
                acc[i][0] += xr[kk] * wv[kk].x;
                acc[i][1] += xr[kk] * wv[kk].y;
                acc[i][2] += xr[kk] * wv[kk].z;
                acc[i][3] += xr[kk] * wv[kk].w;
            }
        }
    }

    float a_s[4], a_d[4];
#pragma unroll
    for (int i = 0; i < 4; i++) {
        a_s[i] = a1[f0 + i];
        a_d[i] = a1[128 + f0 + i];
    }
#pragma unroll
    for (int i = 0; i < 4; i++) {
        int m = base + r0 + i;
        union { __half2 hh[2]; float2 ff; } u;
        u.hh[0] = __floats2half2_rn(acc[i][0], acc[i][1]);
        u.hh[1] = __floats2half2_rn(acc[i][2], acc[i][3]);
        *(float2*)(h1 + (size_t)m * 128 + f0) = u.ff;
        float ps = acc[i][0]*a_s[0] + acc[i][1]*a_s[1] + acc[i][2]*a_s[2] + acc[i][3]*a_s[3];
        float pd = acc[i][0]*a_d[0] + acc[i][1]*a_d[1] + acc[i][2]*a_d[2] + acc[i][3]*a_d[3];
#pragma unroll
        for (int o = 16; o >= 1; o >>= 1) {
            ps += __shfl_xor(ps, o);
            pd += __shfl_xor(pd, o);
        }
        if (tf == 0) {
            ssrc1[m] = ps;
            sdst1[m] = pd;
        }
    }
}

// ---------------- K2: attn1, per-node block (4 waves x 4 batches) ----------------
// out: zbuf (fp32), x2u = r*state (fp16)
__global__ __launch_bounds__(256) void attn1_allb(
    const int* __restrict__ deg, const int* __restrict__ cols,
    const __half* __restrict__ h1, const float* __restrict__ ssrc1,
    const float* __restrict__ sdst1, const float* __restrict__ state,
    float* __restrict__ zbuf, __half* __restrict__ x2u) {
    const int i = blockIdx.x;
    const int t = threadIdx.x, wid = t >> 6, lane = t & 63;
    __shared__ int cl[MAXD];
    __shared__ float wbuf[4][MAXD];
    const int d = deg[i];
    for (int j = t; j < d; j += 256) cl[j] = cols[(size_t)i * MAXD + j];
    __syncthreads();
    float* w = wbuf[wid];
    const int q4 = lane >> 4, fl = lane & 15;

#pragma unroll 1
    for (int qq = 0; qq < 4; qq++) {
        const int b = wid * 4 + qq;
        const size_t mrow = (size_t)b * NN + i;
        const float ssrc = ssrc1[mrow];
        float mx = -1e30f;
        for (int j = lane; j < d; j += 64) {
            float e = ssrc + sdst1[(size_t)b * NN + cl[j]];
            e = e > 0.f ? e : LALPHA * e;
            w[j] = e;
            mx = fmaxf(mx, e);
        }
#pragma unroll
        for (int o = 32; o >= 1; o >>= 1) mx = fmaxf(mx, __shfl_xor(mx, o));
        float sum = 0.f;
        for (int j = lane; j < d; j += 64) {
            float e = __expf(w[j] - mx);
            w[j] = e;
            sum += e;
        }
#pragma unroll
        for (int o = 32; o >= 1; o >>= 1) sum += __shfl_xor(sum, o);
        const float inv = 1.f / sum;

        // fp16 gather: 4 neighbors/iter; 16 lanes per neighbor, 8 cols (16B) per lane
        const __half* hb = h1 + (size_t)b * NN * 128;
        float a8[8] = {};
#pragma unroll 2
        for (int j = 0; j < d; j += 4) {
            int jj = j + q4;
            float wt = (jj < d) ? w[jj] : 0.f;
            int row = cl[(jj < d) ? jj : j];
            union { float4 f; __half2 h[4]; } u;
            u.f = *(const float4*)(hb + (size_t)row * 128 + fl * 8);
#pragma unroll
            for (int k = 0; k < 4; k++) {
                a8[2 * k]     += wt * __low2float(u.h[k]);
                a8[2 * k + 1] += wt * __high2float(u.h[k]);
            }
        }
#pragma unroll
        for (int k = 0; k < 8; k++) {
            a8[k] += __shfl_xor(a8[k], 32);
            a8[k] += __shfl_xor(a8[k], 16);
        }
        // lanes 0-15 hold cols fl*8 .. fl*8+7 of att @ h1

        size_t mo = mrow * 64;
        if (lane < 8) {
            // r gate (gv cols lane*8..+7): x2u = r * state (fp16)
            int c = lane * 8;
            float4 s0 = *(const float4*)(state + mo + c);
            float4 s1 = *(const float4*)(state + mo + c + 4);
            float rs[8];
#pragma unroll
            for (int k = 0; k < 8; k++) rs[k] = 1.f / (1.f + __expf(-a8[k] * inv));
            union { __half2 hh[4]; float4 ff; } u;
            u.hh[0] = __floats2half2_rn(rs[0] * s0.x, rs[1] * s0.y);
            u.hh[1] = __floats2half2_rn(rs[2] * s0.z, rs[3] * s0.w);
            u.hh[2] = __floats2half2_rn(rs[4] * s1.x, rs[5] * s1.y);
            u.hh[3] = __floats2half2_rn(rs[6] * s1.z, rs[7] * s1.w);
            *(float4*)(x2u + mo + c) = u.ff;
        } else if (lane < 16) {
            // z gate (gv cols 64 + (lane-8)*8 ..)
            int c = (lane - 8) * 8;
            float zz[8];
#pragma unroll
            for (int k = 0; k < 8; k++) zz[k] = 1.f / (1.f + __expf(-a8[k] * inv));
            *(float4*)(zbuf + mo + c)     = make_float4(zz[0], zz[1], zz[2], zz[3]);
            *(float4*)(zbuf + mo + c + 4) = make_float4(zz[4], zz[5], zz[6], zz[7]);
        }
    }
}

// ---------------- K3: gemm2 (x2=[X | x2u] @ W2) + score epilogue ----------------
// 64 rows x 64 cols per block, K=128. W2 read once per 64 rows.
__global__ __launch_bounds__(256) void gemm2_score(
    const float* __restrict__ X, const __half* __restrict__ x2u,
    const float* __restrict__ W2, const float* __restrict__ a2,
    __half* __restrict__ h2, float* __restrict__ ssrc2, float* __restrict__ sdst2) {
    __shared__ __align__(16) float xs[64][132];
    int t = threadIdx.x;
    int tf = t & 15, tr = t >> 4;     // col group (4 cols of 64), row group (4 rows)
    int f0 = tf * 4, r0 = tr * 4;
    int base = blockIdx.x * 64;

    for (int idx = t; idx < 64 * 32; idx += 256) {
        int r = idx >> 5, c = (idx & 31) * 4;
        if (c < 64) {
            float4 v = *(const float4*)(X + (size_t)(base + r) * 64 + c);
            xs[r][c] = v.x; xs[r][c + 1] = v.y; xs[r][c + 2] = v.z; xs[r][c + 3] = v.w;
        } else {
            union { float2 f; __half2 h[2]; } u;
            u.f = *(const float2*)(x2u + (size_t)(base + r) * 64 + (c - 64));
            xs[r][c]     = __low2float(u.h[0]);
            xs[r][c + 1] = __high2float(u.h[0]);
            xs[r][c + 2] = __low2float(u.h[1]);
            xs[r][c + 3] = __high2float(u.h[1]);
        }
    }
    __syncthreads();

    float acc[4][4] = {};
    for (int k = 0; k < 128; k += 4) {
        float4 xv[4], wv[4];
#pragma unroll
        for (int i = 0; i < 4; i++) xv[i] = *(const float4*)&xs[r0 + i][k];
#pragma unroll
        for (int i = 0; i < 4; i++) wv[i] = *(const float4*)(W2 + (size_t)(k + i) * 64 + f0);
#pragma unroll
        for (int i = 0; i < 4; i++) {
            float xr[4] = {xv[i].x, xv[i].y, xv[i].z, xv[i].w};
#pragma unroll
            for (int kk = 0; kk < 4; kk++) {
                acc[i][0] += xr[kk] * wv[kk].x;
                acc[i][1] += xr[kk] * wv[kk].y;
                acc[i][2] += xr[kk] * wv[kk].z;
                acc[i][3] += xr[kk] * wv[kk].w;
            }
        }
    }

    float a_s[4], a_d[4];
#pragma unroll
    for (int i = 0; i < 4; i++) {
        a_s[i] = a2[f0 + i];
        a_d[i] = a2[64 + f0 + i];
    }
#pragma unroll
    for (int i = 0; i < 4; i++) {
        int m = base + r0 + i;
        union { __half2 hh[2]; float2 ff; } u;
        u.hh[0] = __floats2half2_rn(acc[i][0], acc[i][1]);
        u.hh[1] = __floats2half2_rn(acc[i][2], acc[i][3]);
        *(float2*)(h2 + (size_t)m * 64 + f0) = u.ff;
        float ps = acc[i][0]*a_s[0] + acc[i][1]*a_s[1] + acc[i][2]*a_s[2] + acc[i][3]*a_s[3];
        float pd = acc[i][0]*a_d[0] + acc[i][1]*a_d[1] + acc[i][2]*a_d[2] + acc[i][3]*a_d[3];
#pragma unroll
        for (int o = 8; o >= 1; o >>= 1) {
            ps += __shfl_xor(ps, o);
            pd += __shfl_xor(pd, o);
        }
        if (tf == 0) {
            ssrc2[m] = ps;
            sdst2[m] = pd;
        }
    }
}

// ---------------- K4: attn2, per-node block (4 waves x 4 batches) + GRU ----------------
__global__ __launch_bounds__(256) void attn2_allb(
    const int* __restrict__ deg, const int* __restrict__ cols,
    const __half* __restrict__ h2, const float* __restrict__ ssrc2,
    const float* __restrict__ sdst2, const float* __restrict__ state,
    const float* __restrict__ zbuf, float* __restrict__ out) {
    const int i = blockIdx.x;
    const int t = threadIdx.x, wid = t >> 6, lane = t & 63;
    __shared__ int cl[MAXD];
    __shared__ float wbuf[4][MAXD];
    const int d = deg[i];
    for (int j = t; j < d; j += 256) cl[j] = cols[(size_t)i * MAXD + j];
    __syncthreads();
    float* w = wbuf[wid];
    const int q8 = lane >> 3, fl = lane & 7;

#pragma unroll 1
    for (int qq = 0; qq < 4; qq++) {
        const int b = wid * 4 + qq;
        const size_t mrow = (size_t)b * NN + i;
        const float ssrc = ssrc2[mrow];
        float mx = -1e30f;
        for (int j = lane; j < d; j += 64) {
            float e = ssrc + sdst2[(size_t)b * NN + cl[j]];
            e = e > 0.f ? e : LALPHA * e;
            w[j] = e;
            mx = fmaxf(mx, e);
        }
#pragma unroll
        for (int o = 32; o >= 1; o >>= 1) mx = fmaxf(mx, __shfl_xor(mx, o));
        float sum = 0.f;
        for (int j = lane; j < d; j += 64) {
            float e = __expf(w[j] - mx);
            w[j] = e;
            sum += e;
        }
#pragma unroll
        for (int o = 32; o >= 1; o >>= 1) sum += __shfl_xor(sum, o);
        const float inv = 1.f / sum;

        // fp16 gather: 8 neighbors/iter; 8 lanes per neighbor, 8 cols (16B) per lane
        const __half* hb = h2 + (size_t)b * NN * 64;
        float a8[8] = {};
#pragma unroll 2
        for (int j = 0; j < d; j += 8) {
            int jj = j + q8;
            float wt = (jj < d) ? w[jj] : 0.f;
            int row = cl[(jj < d) ? jj : j];
            union { float4 f; __half2 h[4]; } u;
            u.f = *(const float4*)(hb + (size_t)row * 64 + fl * 8);
#pragma unroll
            for (int k = 0; k < 4; k++) {
                a8[2 * k]     += wt * __low2float(u.h[k]);
                a8[2 * k + 1] += wt * __high2float(u.h[k]);
            }
        }
#pragma unroll
        for (int k = 0; k < 8; k++) {
            a8[k] += __shfl_xor(a8[k], 32);
            a8[k] += __shfl_xor(a8[k], 16);
            a8[k] += __shfl_xor(a8[k], 8);
        }
        // lanes 0-7 hold cols lane*8 .. lane*8+7

        if (lane < 8) {
            size_t mo = mrow * 64;
            int c = lane * 8;
            float4 z0 = *(const float4*)(zbuf + mo + c);
            float4 z1 = *(const float4*)(zbuf + mo + c + 4);
            float4 s0 = *(const float4*)(state + mo + c);
            float4 s1 = *(const float4*)(state + mo + c + 4);
            float4 o0, o1;
            o0.x = z0.x * s0.x + (1.f - z0.x) * tanhf(a8[0] * inv);
            o0.y = z0.y * s0.y + (1.f - z0.y) * tanhf(a8[1] * inv);
            o0.z = z0.z * s0.z + (1.f - z0.z) * tanhf(a8[2] * inv);
            o0.w = z0.w * s0.w + (1.f - z0.w) * tanhf(a8[3] * inv);
            o1.x = z1.x * s1.x + (1.f - z1.x) * tanhf(a8[4] * inv);
            o1.y = z1.y * s1.y + (1.f - z1.y) * tanhf(a8[5] * inv);
            o1.z = z1.z * s1.z + (1.f - z1.z) * tanhf(a8[6] * inv);
            o1.w = z1.w * s1.w + (1.f - z1.w) * tanhf(a8[7] * inv);
            *(float4*)(out + mo + c)     = o0;
            *(float4*)(out + mo + c + 4) = o1;
        }
    }
}

extern "C" void kernel_launch(void* const* d_in, const int* in_sizes, int n_in,
                              void* d_out, int out_size, void* d_ws, size_t ws_size,
                              hipStream_t stream) {
    const float* X     = (const float*)d_in[0];
    const float* state = (const float*)d_in[1];
    const float* adj   = (const float*)d_in[2];
    const float* W1    = (const float*)d_in[3];
    const float* a1    = (const float*)d_in[4];
    const float* W2    = (const float*)d_in[5];
    const float* a2    = (const float*)d_in[6];
    float* out = (float*)d_out;

    char* ws = (char*)d_ws;
    size_t off = 0;
    auto alloc = [&](size_t bytes) -> void* {
        void* p = ws + off;
        off = (off + bytes + 255) & ~(size_t)255;
        return p;
    };
    int*    deg   = (int*)alloc(NN * sizeof(int));
    int*    cols  = (int*)alloc((size_t)NN * MAXD * sizeof(int));
    __half* h1    = (__half*)alloc((size_t)BB * NN * 128 * sizeof(__half));
    float*  ssrc1 = (float*)alloc((size_t)BB * NN * sizeof(float));
    float*  sdst1 = (float*)alloc((size_t)BB * NN * sizeof(float));
    float*  zbuf  = (float*)alloc((size_t)BB * NN * 64 * sizeof(float));
    __half* x2u   = (__half*)alloc((size_t)BB * NN * 64 * sizeof(__half));
    __half* h2    = (__half*)alloc((size_t)BB * NN * 64 * sizeof(__half));
    float*  ssrc2 = (float*)alloc((size_t)BB * NN * sizeof(float));
    float*  sdst2 = (float*)alloc((size_t)BB * NN * sizeof(float));

    const int M = BB * NN;  // 16384 rows

    csr_gemm1<<<512 + NN, 256, 0, stream>>>(adj, X, state, W1, a1, deg, cols,
                                            h1, ssrc1, sdst1);
    attn1_allb<<<NN, 256, 0, stream>>>(deg, cols, h1, ssrc1, sdst1, state, zbuf, x2u);
    gemm2_score<<<M / 64, 256, 0, stream>>>(X, x2u, W2, a2, h2, ssrc2, sdst2);
    attn2_allb<<<NN, 256, 0, stream>>>(deg, cols, h2, ssrc2, sdst2, state, zbuf, out);
}

// Round 6
// 130.165 us; speedup vs baseline: 1.0933x; 1.0933x over previous
//
#include <hip/hip_runtime.h>
#include <hip/hip_fp16.h>

#define BB 16
#define NN 1024
#define LALPHA 0.2f
#define MAXD 192

// ---------------- K1: fused CSR build (blocks 512..1535) + gemm1 (blocks 0..511) ----------
// gemm1: h1[m,f] = concat(X,state)[m,:] @ W1 (fp16 out) + s_src1/s_dst1 score epilogue.
__global__ __launch_bounds__(256) void csr_gemm1(
    const float* __restrict__ adj, const float* __restrict__ X,
    const float* __restrict__ state, const float* __restrict__ W1,
    const float* __restrict__ a1, int* __restrict__ deg, int* __restrict__ cols,
    __half* __restrict__ h1, float* __restrict__ ssrc1, float* __restrict__ sdst1) {
    __shared__ __align__(16) float xs[32][132];
    __shared__ int cnt;
    int t = threadIdx.x;

    if (blockIdx.x >= 512) {
        // ---- CSR branch: one block per node ----
        int i = blockIdx.x - 512;
        if (t == 0) cnt = 0;
        __syncthreads();
        for (int j = t; j < NN; j += 256) {
            if (adj[(size_t)i * NN + j] > 0.0f) {
                int p = atomicAdd(&cnt, 1);
                if (p < MAXD) cols[(size_t)i * MAXD + p] = j;
            }
        }
        __syncthreads();
        if (t == 0) deg[i] = cnt < MAXD ? cnt : MAXD;
        return;
    }

    // ---- gemm1 branch: 32 rows x 128 cols, K=128 ----
    int tf = t & 31, tr = t >> 5;     // col group (4 cols), row group (4 rows)
    int f0 = tf * 4, r0 = tr * 4;
    int base = blockIdx.x * 32;

    for (int idx = t; idx < 32 * 32; idx += 256) {
        int r = idx >> 5, c = (idx & 31) * 4;
        float4 v = (c < 64) ? *(const float4*)(X + (size_t)(base + r) * 64 + c)
                            : *(const float4*)(state + (size_t)(base + r) * 64 + (c - 64));
        xs[r][c] = v.x; xs[r][c + 1] = v.y; xs[r][c + 2] = v.z; xs[r][c + 3] = v.w;
    }
    __syncthreads();

    float acc[4][4] = {};
    for (int k = 0; k < 128; k += 4) {
        float4 xv[4], wv[4];
#pragma unroll
        for (int i = 0; i < 4; i++) xv[i] = *(const float4*)&xs[r0 + i][k];
#pragma unroll
        for (int i = 0; i < 4; i++) wv[i] = *(const float4*)(W1 + (size_t)(k + i) * 128 + f0);
#pragma unroll
        for (int i = 0; i < 4; i++) {
            float xr[4] = {xv[i].x, xv[i].y, xv[i].z, xv[i].w};
#pragma unroll
            for (int kk = 0; kk < 4; kk++) {
                acc[i][0] += xr[kk] * wv[kk].x;
                acc[i][1] += xr[kk] * wv[kk].y;
                acc[i][2] += xr[kk] * wv[kk].z;
                acc[i][3] += xr[kk] * wv[kk].w;
            }
        }
    }

    float a_s[4], a_d[4];
#pragma unroll
    for (int i = 0; i < 4; i++) {
        a_s[i] = a1[f0 + i];
        a_d[i] = a1[128 + f0 + i];
    }
#pragma unroll
    for (int i = 0; i < 4; i++) {
        int m = base + r0 + i;
        union { __half2 hh[2]; float2 ff; } u;
        u.hh[0] = __floats2half2_rn(acc[i][0], acc[i][1]);
        u.hh[1] = __floats2half2_rn(acc[i][2], acc[i][3]);
        *(float2*)(h1 + (size_t)m * 128 + f0) = u.ff;
        float ps = acc[i][0]*a_s[0] + acc[i][1]*a_s[1] + acc[i][2]*a_s[2] + acc[i][3]*a_s[3];
        float pd = acc[i][0]*a_d[0] + acc[i][1]*a_d[1] + acc[i][2]*a_d[2] + acc[i][3]*a_d[3];
#pragma unroll
        for (int o = 16; o >= 1; o >>= 1) {
            ps += __shfl_xor(ps, o);
            pd += __shfl_xor(pd, o);
        }
        if (tf == 0) {
            ssrc1[m] = ps;
            sdst1[m] = pd;
        }
    }
}

// ---------------- K2: attn1 (F=128, fp16 gather) + gates + fused gemm2 ----------------
__global__ __launch_bounds__(64) void attn1_fused(
    const int* __restrict__ deg, const int* __restrict__ cols,
    const __half* __restrict__ h1, const float* __restrict__ s_src,
    const float* __restrict__ s_dst, const float* __restrict__ state,
    const float* __restrict__ X, const float* __restrict__ W2,
    const float* __restrict__ a2, float* __restrict__ zbuf,
    __half* __restrict__ h2, float* __restrict__ ssrc2, float* __restrict__ sdst2) {
    int bi = blockIdx.x;
    int i = bi & (NN - 1);
    int b = bi >> 10;
    int lane = threadIdx.x;
    int d = deg[i];
    float ssrc = s_src[bi];
    __shared__ float w[MAXD];
    __shared__ int cl[MAXD];
    __shared__ __align__(16) float x2[128];
    for (int j = lane; j < d; j += 64) cl[j] = cols[(size_t)i * MAXD + j];
    __syncthreads();
    float mx = -1e30f;
    for (int j = lane; j < d; j += 64) {
        float e = ssrc + s_dst[b * NN + cl[j]];
        e = e > 0.f ? e : LALPHA * e;
        w[j] = e;
        mx = fmaxf(mx, e);
    }
#pragma unroll
    for (int o = 32; o >= 1; o >>= 1) mx = fmaxf(mx, __shfl_xor(mx, o));
    float sum = 0.f;
    for (int j = lane; j < d; j += 64) {
        float e = __expf(w[j] - mx);
        w[j] = e;
        sum += e;
    }
#pragma unroll
    for (int o = 32; o >= 1; o >>= 1) sum += __shfl_xor(sum, o);
    __syncthreads();
    float inv = 1.f / sum;

    // fp16 gather: 4 neighbors/iter; 16 lanes per neighbor, 8 cols (16B) per lane
    int q = lane >> 4, fl = lane & 15;
    const __half* hb = h1 + (size_t)b * NN * 128;
    float a8[8] = {};
#pragma unroll 2
    for (int j = 0; j < d; j += 4) {
        int jj = j + q;
        float wt = (jj < d) ? w[jj] : 0.f;
        int row = cl[(jj < d) ? jj : j];
        union { float4 f; __half2 h[4]; } u;
        u.f = *(const float4*)(hb + (size_t)row * 128 + fl * 8);
#pragma unroll
        for (int k = 0; k < 4; k++) {
            a8[2 * k]     += wt * __low2float(u.h[k]);
            a8[2 * k + 1] += wt * __high2float(u.h[k]);
        }
    }
#pragma unroll
    for (int k = 0; k < 8; k++) {
        a8[k] += __shfl_xor(a8[k], 32);
        a8[k] += __shfl_xor(a8[k], 16);
    }
    // lanes 0-15 hold cols fl*8 .. fl*8+7 of att @ h1

    size_t mo = (size_t)bi * 64;
    if (lane < 8) {
        // r gate (cols lane*8..+7) -> x2 upper half = r * state
        int c = lane * 8;
        float4 s0 = *(const float4*)(state + mo + c);
        float4 s1 = *(const float4*)(state + mo + c + 4);
        float rs[8];
#pragma unroll
        for (int k = 0; k < 8; k++) rs[k] = 1.f / (1.f + __expf(-a8[k] * inv));
        *(float4*)&x2[64 + c]     = make_float4(rs[0]*s0.x, rs[1]*s0.y, rs[2]*s0.z, rs[3]*s0.w);
        *(float4*)&x2[64 + c + 4] = make_float4(rs[4]*s1.x, rs[5]*s1.y, rs[6]*s1.z, rs[7]*s1.w);
    } else if (lane < 16) {
        // z gate (cols 64 + (lane-8)*8 ..)
        int c = (lane - 8) * 8;
        float zz[8];
#pragma unroll
        for (int k = 0; k < 8; k++) zz[k] = 1.f / (1.f + __expf(-a8[k] * inv));
        *(float4*)(zbuf + mo + c)     = make_float4(zz[0], zz[1], zz[2], zz[3]);
        *(float4*)(zbuf + mo + c + 4) = make_float4(zz[4], zz[5], zz[6], zz[7]);
    } else if (lane < 32) {
        *(float4*)&x2[(lane - 16) * 4] = *(const float4*)(X + mo + (lane - 16) * 4);
    }
    __syncthreads();

    // fused gemm2 matvec: h2_m[lane] = sum_k x2[k] * W2[k][lane]  (fp32 math)
    float hacc = 0.f;
#pragma unroll 8
    for (int k = 0; k < 128; k += 4) {
        float4 xv = *(const float4*)&x2[k];
        hacc += xv.x * W2[(size_t)(k + 0) * 64 + lane];
        hacc += xv.y * W2[(size_t)(k + 1) * 64 + lane];
        hacc += xv.z * W2[(size_t)(k + 2) * 64 + lane];
        hacc += xv.w * W2[(size_t)(k + 3) * 64 + lane];
    }
    h2[mo + lane] = __float2half_rn(hacc);
    float ps = hacc * a2[lane];
    float pd = hacc * a2[64 + lane];
#pragma unroll
    for (int o = 32; o >= 1; o >>= 1) {
        ps += __shfl_xor(ps, o);
        pd += __shfl_xor(pd, o);
    }
    if (lane == 0) {
        ssrc2[bi] = ps;
        sdst2[bi] = pd;
    }
}

// ---------------- K3: attn2 (F=64, fp16 gather) + tanh + GRU combine ----------------
__global__ __launch_bounds__(64) void attn2_kernel(
    const int* __restrict__ deg, const int* __restrict__ cols,
    const __half* __restrict__ h2, const float* __restrict__ s_src,
    const float* __restrict__ s_dst, const float* __restrict__ state,
    const float* __restrict__ zbuf, float* __restrict__ out) {
    int bi = blockIdx.x;
    int i = bi & (NN - 1);
    int b = bi >> 10;
    int lane = threadIdx.x;
    int d = deg[i];
    float ssrc = s_src[bi];
    __shared__ float w[MAXD];
    __shared__ int cl[MAXD];
    for (int j = lane; j < d; j += 64) cl[j] = cols[(size_t)i * MAXD + j];
    __syncthreads();
    float mx = -1e30f;
    for (int j = lane; j < d; j += 64) {
        float e = ssrc + s_dst[b * NN + cl[j]];
        e = e > 0.f ? e : LALPHA * e;
        w[j] = e;
        mx = fmaxf(mx, e);
    }
#pragma unroll
    for (int o = 32; o >= 1; o >>= 1) mx = fmaxf(mx, __shfl_xor(mx, o));
    float sum = 0.f;
    for (int j = lane; j < d; j += 64) {
        float e = __expf(w[j] - mx);
        w[j] = e;
        sum += e;
    }
#pragma unroll
    for (int o = 32; o >= 1; o >>= 1) sum += __shfl_xor(sum, o);
    __syncthreads();
    float inv = 1.f / sum;

    // fp16 gather: 8 neighbors/iter; 8 lanes per neighbor, 8 cols (16B) per lane
    int q = lane >> 3, fl = lane & 7;
    const __half* hb = h2 + (size_t)b * NN * 64;
    float a8[8] = {};
#pragma unroll 2
    for (int j = 0; j < d; j += 8) {
        int jj = j + q;
        float wt = (jj < d) ? w[jj] : 0.f;
        int row = cl[(jj < d) ? jj : j];
        union { float4 f; __half2 h[4]; } u;
        u.f = *(const float4*)(hb + (size_t)row * 64 + fl * 8);
#pragma unroll
        for (int k = 0; k < 4; k++) {
            a8[2 * k]     += wt * __low2float(u.h[k]);
            a8[2 * k + 1] += wt * __high2float(u.h[k]);
        }
    }
#pragma unroll
    for (int k = 0; k < 8; k++) {
        a8[k] += __shfl_xor(a8[k], 32);
        a8[k] += __shfl_xor(a8[k], 16);
        a8[k] += __shfl_xor(a8[k], 8);
    }
    // lanes 0-7 hold cols lane*8 .. lane*8+7

    if (lane < 8) {
        size_t mo = (size_t)bi * 64;
        int c = lane * 8;
        float4 z0 = *(const float4*)(zbuf + mo + c);
        float4 z1 = *(const float4*)(zbuf + mo + c + 4);
        float4 s0 = *(const float4*)(state + mo + c);
        float4 s1 = *(const float4*)(state + mo + c + 4);
        float4 o0, o1;
        o0.x = z0.x * s0.x + (1.f - z0.x) * tanhf(a8[0] * inv);
        o0.y = z0.y * s0.y + (1.f - z0.y) * tanhf(a8[1] * inv);
        o0.z = z0.z * s0.z + (1.f - z0.z) * tanhf(a8[2] * inv);
        o0.w = z0.w * s0.w + (1.f - z0.w) * tanhf(a8[3] * inv);
        o1.x = z1.x * s1.x + (1.f - z1.x) * tanhf(a8[4] * inv);
        o1.y = z1.y * s1.y + (1.f - z1.y) * tanhf(a8[5] * inv);
        o1.z = z1.z * s1.z + (1.f - z1.z) * tanhf(a8[6] * inv);
        o1.w = z1.w * s1.w + (1.f - z1.w) * tanhf(a8[7] * inv);
        *(float4*)(out + mo + c)     = o0;
        *(float4*)(out + mo + c + 4) = o1;
    }
}

extern "C" void kernel_launch(void* const* d_in, const int* in_sizes, int n_in,
                              void* d_out, int out_size, void* d_ws, size_t ws_size,
                              hipStream_t stream) {
    const float* X     = (const float*)d_in[0];
    const float* state = (const float*)d_in[1];
    const float* adj   = (const float*)d_in[2];
    const float* W1    = (const float*)d_in[3];
    const float* a1    = (const float*)d_in[4];
    const float* W2    = (const float*)d_in[5];
    const float* a2    = (const float*)d_in[6];
    float* out = (float*)d_out;

    char* ws = (char*)d_ws;
    size_t off = 0;
    auto alloc = [&](size_t bytes) -> void* {
        void* p = ws + off;
        off = (off + bytes + 255) & ~(size_t)255;
        return p;
    };
    int*    deg   = (int*)alloc(NN * sizeof(int));
    int*    cols  = (int*)alloc((size_t)NN * MAXD * sizeof(int));
    __half* h1    = (__half*)alloc((size_t)BB * NN * 128 * sizeof(__half));
    float*  ssrc1 = (float*)alloc((size_t)BB * NN * sizeof(float));
    float*  sdst1 = (float*)alloc((size_t)BB * NN * sizeof(float));
    float*  zbuf  = (float*)alloc((size_t)BB * NN * 64 * sizeof(float));
    __half* h2    = (__half*)alloc((size_t)BB * NN * 64 * sizeof(__half));
    float*  ssrc2 = (float*)alloc((size_t)BB * NN * sizeof(float));
    float*  sdst2 = (float*)alloc((size_t)BB * NN * sizeof(float));

    const int M = BB * NN;  // 16384 rows

    csr_gemm1<<<512 + NN, 256, 0, stream>>>(adj, X, state, W1, a1, deg, cols,
                                            h1, ssrc1, sdst1);
    attn1_fused<<<M, 64, 0, stream>>>(deg, cols, h1, ssrc1, sdst1, state, X, W2, a2,
                                      zbuf, h2, ssrc2, sdst2);
    attn2_kernel<<<M, 64, 0, stream>>>(deg, cols, h2, ssrc2, sdst2, state, zbuf, out);
}